// Round 4
// baseline (44.311 us; speedup 1.0000x reference)
//
#include <hip/hip_runtime.h>

#define NQ 8
#define NL 4
#define BATCH 8192

__device__ __forceinline__ float rdl(float v, int lane) {
    return __int_as_float(__builtin_amdgcn_readlane(__float_as_int(v), lane));
}

// 16 lanes per sample, 2 samples per thread (A,B). Lane bits g3..g0 = wires 0-3,
// register bits k3..k0 = wires 4-7. 32 independent amp chains per thread.
__global__ __launch_bounds__(256) void qsim(const float* __restrict__ x,
                                            const float* __restrict__ w,
                                            float* __restrict__ out)
{
    const int tid = blockIdx.x * blockDim.x + threadIdx.x;
    const int grp = tid >> 4;              // group id in [0, BATCH/2)
    const int g   = threadIdx.x & 15;
    const int sA  = grp;
    const int sB  = grp + (BATCH / 2);

    // ---- wave-uniform layer coefficients, one (layer,wire) per lane ----
    // lane t (t<32): layer = t>>3, wire = t&7.
    // wire<4 (lane wires, fused RZ+RY): {ch, cz, sh, sz} (half-angles)
    // wire>=4 (reg wires): {cos(t/2), sin(t/2), cos(ph), sin(ph)}
    float cw0, cw1, cw2, cw3;
    {
        const int t  = threadIdx.x & 31;
        const int li = t >> 3;
        const int wi = t & 7;
        float th = w[(li * NQ + wi) * 2 + 0];
        float ph = w[(li * NQ + wi) * 2 + 1];
        float c = __cosf(0.5f * th), s = __sinf(0.5f * th);
        float h = __cosf(0.5f * ph), z = __sinf(0.5f * ph);
        bool lw = (wi < 4);
        cw0 = lw ? c * h : c;
        cw1 = lw ? c * z : s;
        cw2 = lw ? s * h : fmaf(-2.0f * z, z, 1.0f);   // cos(ph) via double angle
        cw3 = lw ? s * z : 2.0f * h * z;               // sin(ph)
    }

    // ---- encoding: real product states ----
    float rA[16], iA[16], rB[16], iB[16];
    {
        const float4* xa = (const float4*)(x + sA * NQ);
        const float4* xb = (const float4*)(x + sB * NQ);
        float4 a0 = xa[0], a1 = xa[1], b0 = xb[0], b1 = xb[1];
        float xeA[8] = {a0.x, a0.y, a0.z, a0.w, a1.x, a1.y, a1.z, a1.w};
        float xeB[8] = {b0.x, b0.y, b0.z, b0.w, b1.x, b1.y, b1.z, b1.w};
        float ceA[8], seA[8], ceB[8], seB[8];
        #pragma unroll
        for (int i = 0; i < 8; ++i) {
            float wv = w[2 * i];
            float aa = 0.5f * (xeA[i] + wv);
            float ab = 0.5f * (xeB[i] + wv);
            ceA[i] = __cosf(aa); seA[i] = __sinf(aa);
            ceB[i] = __cosf(ab); seB[i] = __sinf(ab);
        }
        float PA = ((g & 8) ? seA[0] : ceA[0]) * ((g & 4) ? seA[1] : ceA[1])
                 * ((g & 2) ? seA[2] : ceA[2]) * ((g & 1) ? seA[3] : ceA[3]);
        float PB = ((g & 8) ? seB[0] : ceB[0]) * ((g & 4) ? seB[1] : ceB[1])
                 * ((g & 2) ? seB[2] : ceB[2]) * ((g & 1) ? seB[3] : ceB[3]);
        #pragma unroll
        for (int k = 0; k < 16; ++k) {
            float fA = ((k & 8) ? seA[4] : ceA[4]) * ((k & 4) ? seA[5] : ceA[5])
                     * ((k & 2) ? seA[6] : ceA[6]) * ((k & 1) ? seA[7] : ceA[7]);
            float fB = ((k & 8) ? seB[4] : ceB[4]) * ((k & 4) ? seB[5] : ceB[5])
                     * ((k & 2) ? seB[6] : ceB[6]) * ((k & 1) ? seB[7] : ceB[7]);
            rA[k] = PA * fA; iA[k] = 0.0f;
            rB[k] = PB * fB; iB[k] = 0.0f;
        }
    }

    const int  src = (threadIdx.x & 48) | ((g ^ (g >> 1)) & 15);
    const bool cc  = (g & 1);

    #pragma unroll 1
    for (int l = 0; l < NL; ++l) {
        const int lb = l * 8;

        // CNOT(0,1),(1,2),(2,3): lane perm; CNOT(3,4)+reg-Gray folded (per sample
        // to cap live temps at 32 extra regs)
        {
            float tr[16], ti[16];
            #pragma unroll
            for (int k = 0; k < 16; ++k) {
                tr[k] = __shfl(rA[k], src, 64);
                ti[k] = __shfl(iA[k], src, 64);
            }
            #pragma unroll
            for (int k = 0; k < 16; ++k) {
                int s0 = k ^ (k >> 1);
                rA[k] = cc ? tr[s0 ^ 8] : tr[s0];
                iA[k] = cc ? ti[s0 ^ 8] : ti[s0];
            }
        }
        {
            float tr[16], ti[16];
            #pragma unroll
            for (int k = 0; k < 16; ++k) {
                tr[k] = __shfl(rB[k], src, 64);
                ti[k] = __shfl(iB[k], src, 64);
            }
            #pragma unroll
            for (int k = 0; k < 16; ++k) {
                int s0 = k ^ (k >> 1);
                rB[k] = cc ? tr[s0 ^ 8] : tr[s0];
                iB[k] = cc ? ti[s0 ^ 8] : ti[s0];
            }
        }
        // CNOT(7,0): control = reg bit k0, target = lane bit g3
        #pragma unroll
        for (int k = 1; k < 16; k += 2) {
            rA[k] = __shfl_xor(rA[k], 8, 64); iA[k] = __shfl_xor(iA[k], 8, 64);
            rB[k] = __shfl_xor(rB[k], 8, 64); iB[k] = __shfl_xor(iB[k], 8, 64);
        }

        // lane wires 0..3: fused RZ+RY (A and B interleaved)
        #pragma unroll
        for (int i = 0; i < 4; ++i) {
            const int mg = 8 >> i;
            const int cl = lb + i;
            float Ar  = rdl(cw0, cl);
            float AiM = rdl(cw1, cl);
            float BrM = rdl(cw2, cl);
            float SZ  = rdl(cw3, cl);
            float Ai = (g & mg) ? AiM : -AiM;
            float Br = (g & mg) ? BrM : -BrM;
            #pragma unroll
            for (int k = 0; k < 16; ++k) {
                float brA = __shfl_xor(rA[k], mg, 64);
                float biA = __shfl_xor(iA[k], mg, 64);
                float brB = __shfl_xor(rB[k], mg, 64);
                float biB = __shfl_xor(iB[k], mg, 64);
                float arA = rA[k], aiA = iA[k];
                rA[k] = Ar * arA - Ai * aiA + Br * brA + SZ * biA;
                iA[k] = Ar * aiA + Ai * arA + Br * biA - SZ * brA;
                float arB = rB[k], aiB = iB[k];
                rB[k] = Ar * arB - Ai * aiB + Br * brB + SZ * biB;
                iB[k] = Ar * aiB + Ai * arB + Br * biB - SZ * brB;
            }
        }

        // reg wires 4..7: RZ = diag(1, e^{i ph}) then RY
        #pragma unroll
        for (int i = 0; i < 4; ++i) {
            const int mk = 8 >> i;
            const int cl = lb + 4 + i;
            float cy = rdl(cw0, cl), sy = rdl(cw1, cl);
            float cf = rdl(cw2, cl), sf = rdl(cw3, cl);
            #pragma unroll
            for (int k = 0; k < 16; ++k) {
                if (!(k & mk)) continue;
                float r, q;
                r = rA[k]; q = iA[k];
                rA[k] = r * cf - q * sf; iA[k] = q * cf + r * sf;
                r = rB[k]; q = iB[k];
                rB[k] = r * cf - q * sf; iB[k] = q * cf + r * sf;
            }
            #pragma unroll
            for (int k = 0; k < 16; ++k) {
                if (k & mk) continue;
                int k1 = k | mk;
                float ar, ai, br, bi;
                ar = rA[k]; ai = iA[k]; br = rA[k1]; bi = iA[k1];
                rA[k]  = cy * ar - sy * br;  iA[k]  = cy * ai - sy * bi;
                rA[k1] = sy * ar + cy * br;  iA[k1] = sy * ai + cy * bi;
                ar = rB[k]; ai = iB[k]; br = rB[k1]; bi = iB[k1];
                rB[k]  = cy * ar - sy * br;  iB[k]  = cy * ai - sy * bi;
                rB[k1] = sy * ar + cy * br;  iB[k1] = sy * ai + cy * bi;
            }
        }
    }

    // ---- measurement ----
    float mtA = 0, m4A = 0, m5A = 0, m6A = 0, m7A = 0;
    float mtB = 0, m4B = 0, m5B = 0, m6B = 0, m7B = 0;
    #pragma unroll
    for (int k = 0; k < 16; ++k) {
        float pA = rA[k] * rA[k] + iA[k] * iA[k];
        float pB = rB[k] * rB[k] + iB[k] * iB[k];
        mtA += pA;                        mtB += pB;
        m4A += (k & 8) ? -pA : pA;        m4B += (k & 8) ? -pB : pB;
        m5A += (k & 4) ? -pA : pA;        m5B += (k & 4) ? -pB : pB;
        m6A += (k & 2) ? -pA : pA;        m6B += (k & 2) ? -pB : pB;
        m7A += (k & 1) ? -pA : pA;        m7B += (k & 1) ? -pB : pB;
    }
    float m0A = (g & 8) ? -mtA : mtA,  m0B = (g & 8) ? -mtB : mtB;
    float m1A = (g & 4) ? -mtA : mtA,  m1B = (g & 4) ? -mtB : mtB;
    float m2A = (g & 2) ? -mtA : mtA,  m2B = (g & 2) ? -mtB : mtB;
    float m3A = (g & 1) ? -mtA : mtA,  m3B = (g & 1) ? -mtB : mtB;
    #pragma unroll
    for (int d = 1; d < 16; d <<= 1) {
        m0A += __shfl_xor(m0A, d, 64);  m0B += __shfl_xor(m0B, d, 64);
        m1A += __shfl_xor(m1A, d, 64);  m1B += __shfl_xor(m1B, d, 64);
        m2A += __shfl_xor(m2A, d, 64);  m2B += __shfl_xor(m2B, d, 64);
        m3A += __shfl_xor(m3A, d, 64);  m3B += __shfl_xor(m3B, d, 64);
        m4A += __shfl_xor(m4A, d, 64);  m4B += __shfl_xor(m4B, d, 64);
        m5A += __shfl_xor(m5A, d, 64);  m5B += __shfl_xor(m5B, d, 64);
        m6A += __shfl_xor(m6A, d, 64);  m6B += __shfl_xor(m6B, d, 64);
        m7A += __shfl_xor(m7A, d, 64);  m7B += __shfl_xor(m7B, d, 64);
    }

    if (g == 0) {
        float4* oa = (float4*)(out + sA * NQ);
        oa[0] = make_float4(m0A, m1A, m2A, m3A);
        oa[1] = make_float4(m4A, m5A, m6A, m7A);
        float4* ob = (float4*)(out + sB * NQ);
        ob[0] = make_float4(m0B, m1B, m2B, m3B);
        ob[1] = make_float4(m4B, m5B, m6B, m7B);
    }
}

extern "C" void kernel_launch(void* const* d_in, const int* in_sizes, int n_in,
                              void* d_out, int out_size, void* d_ws, size_t ws_size,
                              hipStream_t stream)
{
    const float* x = (const float*)d_in[0];
    const float* w = (const float*)d_in[1];
    float* out = (float*)d_out;
    dim3 block(256);
    dim3 grid((BATCH / 2 * 16) / 256);   // 256 blocks; 2 samples per thread
    qsim<<<grid, block, 0, stream>>>(x, w, out);
}

// Round 5
// 26.560 us; speedup vs baseline: 1.6683x; 1.6683x over previous
//
#include <hip/hip_runtime.h>

#define BATCH 8192

typedef __attribute__((ext_vector_type(8))) short bf16x8;
typedef __attribute__((ext_vector_type(4))) float f32x4;

__device__ __forceinline__ unsigned short f2bf(float f) {
    unsigned int u = __float_as_uint(f);
    u += 0x7fffu + ((u >> 16) & 1u);      // RTNE
    return (unsigned short)(u >> 16);
}
__device__ __forceinline__ float rfl(float v) {
    return __int_as_float(__builtin_amdgcn_readfirstlane(__float_as_int(v)));
}

// ---------------------------------------------------------------------------
// Kernel P: blocks 0..255 build in_state bf16 [8192][256] (sample-major).
//           blocks 256..319 build U bf16 [512][256]: rows 0-255 Re, 256-511 Im,
//           column c = basis state. Gate code identical to the verified R3 body.
// State-index convention: bit (7-w) of the index = wire w.
// ---------------------------------------------------------------------------
__global__ __launch_bounds__(256) void prep(const float* __restrict__ x,
                                            const float* __restrict__ w,
                                            unsigned short* __restrict__ inb,
                                            unsigned short* __restrict__ Ub)
{
    const int bid = blockIdx.x;
    if (bid < 256) {
        // ---- in_state: thread t -> sample bid*32 + (t>>3), j-chunk (t&7)*32 ----
        const int t  = threadIdx.x;
        const int s  = bid * 32 + (t >> 3);
        const int jc = (t & 7) * 32;
        const float4* xv = (const float4*)(x + s * 8);
        float4 x0 = xv[0], x1 = xv[1];
        float xe[8] = {x0.x, x0.y, x0.z, x0.w, x1.x, x1.y, x1.z, x1.w};
        float ce[8], se[8];
        #pragma unroll
        for (int i = 0; i < 8; ++i) {
            float a = 0.5f * (xe[i] + w[2 * i]);
            ce[i] = __cosf(a); se[i] = __sinf(a);
        }
        float p45[4] = {ce[4]*ce[5], ce[4]*se[5], se[4]*ce[5], se[4]*se[5]};
        float p67[4] = {ce[6]*ce[7], ce[6]*se[7], se[6]*ce[7], se[6]*se[7]};
        const int j1b = (t & 7) * 2;
        float A0, A1;
        {
            int j1 = j1b;
            A0 = ((j1&8)?se[0]:ce[0])*((j1&4)?se[1]:ce[1])*((j1&2)?se[2]:ce[2])*((j1&1)?se[3]:ce[3]);
            j1 = j1b + 1;
            A1 = ((j1&8)?se[0]:ce[0])*((j1&4)?se[1]:ce[1])*((j1&2)?se[2]:ce[2])*((j1&1)?se[3]:ce[3]);
        }
        unsigned int wb[16];
        #pragma unroll
        for (int e2 = 0; e2 < 16; ++e2) {
            int e  = e2 * 2;
            float Aa = (e2 < 8) ? A0 : A1;
            int j2a = e & 15, j2b = (e + 1) & 15;
            float va = Aa * p45[j2a >> 2] * p67[j2a & 3];
            float vb = Aa * p45[j2b >> 2] * p67[j2b & 3];
            wb[e2] = (unsigned int)f2bf(va) | ((unsigned int)f2bf(vb) << 16);
        }
        uint4* dst = (uint4*)(inb + s * 256 + jc);
        dst[0] = make_uint4(wb[0],  wb[1],  wb[2],  wb[3]);
        dst[1] = make_uint4(wb[4],  wb[5],  wb[6],  wb[7]);
        dst[2] = make_uint4(wb[8],  wb[9],  wb[10], wb[11]);
        dst[3] = make_uint4(wb[12], wb[13], wb[14], wb[15]);
    } else {
        // ---- U column c per wave; lane bits l5..l0 = wires 0-5, regs k1k0 = wires 6,7
        const int l = threadIdx.x & 63;
        const int c = (bid - 256) * 4 + (threadIdx.x >> 6);
        float re[4], im[4];
        const bool ls = (l == (c >> 2));
        #pragma unroll
        for (int k = 0; k < 4; ++k) {
            re[k] = (ls && ((c & 3) == k)) ? 1.0f : 0.0f;
            im[k] = 0.0f;
        }
        const int  src = (l ^ (l >> 1)) & 63;
        const bool c5  = (l & 1);
        #pragma unroll 1
        for (int layer = 0; layer < 4; ++layer) {
            const float* wl = w + layer * 16;
            float tr[4], ti[4];
            #pragma unroll
            for (int k = 0; k < 4; ++k) {
                tr[k] = __shfl(re[k], src, 64);
                ti[k] = __shfl(im[k], src, 64);
            }
            re[0] = c5 ? tr[2] : tr[0];  im[0] = c5 ? ti[2] : ti[0];
            re[1] = c5 ? tr[3] : tr[1];  im[1] = c5 ? ti[3] : ti[1];
            re[2] = c5 ? tr[1] : tr[3];  im[2] = c5 ? ti[1] : ti[3];
            re[3] = c5 ? tr[0] : tr[2];  im[3] = c5 ? ti[0] : ti[2];
            re[1] = __shfl_xor(re[1], 32, 64); im[1] = __shfl_xor(im[1], 32, 64);
            re[3] = __shfl_xor(re[3], 32, 64); im[3] = __shfl_xor(im[3], 32, 64);
            #pragma unroll
            for (int i = 0; i < 6; ++i) {
                float cth = __cosf(0.5f * wl[2*i]),     sth = __sinf(0.5f * wl[2*i]);
                float cph = __cosf(0.5f * wl[2*i+1]),   sph = __sinf(0.5f * wl[2*i+1]);
                float Ar = rfl(cth * cph), SZ = rfl(sth * sph);
                float sgn = (l & (32 >> i)) ? 1.0f : -1.0f;
                float Ai = sgn * rfl(cth * sph);
                float Br = sgn * rfl(sth * cph);
                const int m = 32 >> i;
                #pragma unroll
                for (int k = 0; k < 4; ++k) {
                    float br = __shfl_xor(re[k], m, 64);
                    float bi = __shfl_xor(im[k], m, 64);
                    float ar = re[k], ai = im[k];
                    re[k] = Ar*ar - Ai*ai + Br*br + SZ*bi;
                    im[k] = Ar*ai + Ai*ar + Br*bi - SZ*br;
                }
            }
            #pragma unroll
            for (int i = 0; i < 2; ++i) {
                float cy = rfl(__cosf(0.5f * wl[12 + 2*i]));
                float sy = rfl(__sinf(0.5f * wl[12 + 2*i]));
                float cf = rfl(__cosf(wl[13 + 2*i]));
                float sf = rfl(__sinf(wl[13 + 2*i]));
                const int mk = 2 >> i;
                #pragma unroll
                for (int k = 0; k < 4; ++k) {
                    if (!(k & mk)) continue;
                    float r = re[k], q = im[k];
                    re[k] = r * cf - q * sf;
                    im[k] = q * cf + r * sf;
                }
                #pragma unroll
                for (int k = 0; k < 4; ++k) {
                    if (k & mk) continue;
                    int k1 = k | mk;
                    float ar = re[k], ai = im[k], br = re[k1], bi = im[k1];
                    re[k]  = cy * ar - sy * br;
                    im[k]  = cy * ai - sy * bi;
                    re[k1] = sy * ar + cy * br;
                    im[k1] = sy * ai + cy * bi;
                }
            }
        }
        #pragma unroll
        for (int k = 0; k < 4; ++k) {
            int i = l * 4 + k;
            Ub[i * 256 + c]         = f2bf(re[k]);
            Ub[(256 + i) * 256 + c] = f2bf(im[k]);
        }
    }
}

// ---------------------------------------------------------------------------
// Kernel G: C[512][8192] = U * in, fused |.|^2 + signed-sum epilogue.
// Block: 4 waves, 32 samples; wave wid owns amp rows [64*wid, 64*wid+64)
// (Re tiles mt=0..3, Im tiles mt=4..7) so p = Re^2+Im^2 stays in-register.
// MFMA 16x16x32 bf16: A row = lane&15, k = (lane>>4)*8+e; B col = lane&15,
// same k; D col = lane&15, row = (lane>>4)*4 + reg  [m89-verified layout].
// ---------------------------------------------------------------------------
__global__ __launch_bounds__(256) void qgemm(const unsigned short* __restrict__ inb,
                                             const unsigned short* __restrict__ Ub,
                                             float* __restrict__ out)
{
    __shared__ float Ps[16][289];   // [contributor ct][snt*9 + e], bank-conflict-free
    const int wid  = threadIdx.x >> 6;
    const int lane = threadIdx.x & 63;
    const int mrow = lane & 15;
    const int kgrp = lane >> 4;
    const int s0   = blockIdx.x * 32;

    f32x4 acc[8][2];
    #pragma unroll
    for (int a = 0; a < 8; ++a)
        #pragma unroll
        for (int b = 0; b < 2; ++b)
            acc[a][b] = (f32x4){0.f, 0.f, 0.f, 0.f};

    #pragma unroll
    for (int ks = 0; ks < 8; ++ks) {
        const int k0 = ks * 32 + kgrp * 8;
        bf16x8 bfr0 = *(const bf16x8*)(inb + (s0 + mrow) * 256 + k0);
        bf16x8 bfr1 = *(const bf16x8*)(inb + (s0 + 16 + mrow) * 256 + k0);
        #pragma unroll
        for (int mt = 0; mt < 8; ++mt) {
            const int row = (mt < 4) ? (wid * 64 + mt * 16 + mrow)
                                     : (256 + wid * 64 + (mt - 4) * 16 + mrow);
            bf16x8 afr = *(const bf16x8*)(Ub + row * 256 + k0);
            acc[mt][0] = __builtin_amdgcn_mfma_f32_16x16x32_bf16(afr, bfr0, acc[mt][0], 0, 0, 0);
            acc[mt][1] = __builtin_amdgcn_mfma_f32_16x16x32_bf16(afr, bfr1, acc[mt][1], 0, 0, 0);
        }
    }

    // epilogue: amp index i = 64*wid + mtl*16 + kgrp*4 + r  (bit 7-w = wire w)
    const int ct = wid * 4 + kgrp;
    #pragma unroll
    for (int nt = 0; nt < 2; ++nt) {
        float am[4], r2m[4], r1m[4];
        #pragma unroll
        for (int mtl = 0; mtl < 4; ++mtl) {
            float p0 = acc[mtl][nt][0]*acc[mtl][nt][0] + acc[mtl+4][nt][0]*acc[mtl+4][nt][0];
            float p1 = acc[mtl][nt][1]*acc[mtl][nt][1] + acc[mtl+4][nt][1]*acc[mtl+4][nt][1];
            float p2 = acc[mtl][nt][2]*acc[mtl][nt][2] + acc[mtl+4][nt][2]*acc[mtl+4][nt][2];
            float p3 = acc[mtl][nt][3]*acc[mtl][nt][3] + acc[mtl+4][nt][3]*acc[mtl+4][nt][3];
            float t0 = p0 + p1, t1 = p2 + p3;
            am[mtl]  = t0 + t1;
            r2m[mtl] = t0 - t1;                    // wire6: sign by r>>1
            r1m[mtl] = (p0 - p1) + (p2 - p3);      // wire7: sign by r&1
        }
        float ps = (am[0] + am[1]) + (am[2] + am[3]);
        float m2 = (am[0] + am[1]) - (am[2] + am[3]);    // wire2: mtl>>1
        float m3 = (am[0] - am[1]) + (am[2] - am[3]);    // wire3: mtl&1
        float m6 = (r2m[0] + r2m[1]) + (r2m[2] + r2m[3]);
        float m7 = (r1m[0] + r1m[1]) + (r1m[2] + r1m[3]);
        float m0 = (wid >= 2) ? -ps : ps;                // wire0: bit7
        float m1 = (wid & 1)  ? -ps : ps;                // wire1: bit6
        float m4 = (kgrp & 2) ? -ps : ps;                // wire4: bit3
        float m5 = (kgrp & 1) ? -ps : ps;                // wire5: bit2
        const int snt = nt * 16 + mrow;
        float* pp = &Ps[ct][snt * 9];
        pp[0]=m0; pp[1]=m1; pp[2]=m2; pp[3]=m3; pp[4]=m4; pp[5]=m5; pp[6]=m6; pp[7]=m7;
    }
    __syncthreads();
    if (threadIdx.x < 32) {
        const int s = threadIdx.x;
        float r[8] = {0,0,0,0,0,0,0,0};
        #pragma unroll
        for (int u = 0; u < 16; ++u)
            #pragma unroll
            for (int e = 0; e < 8; ++e)
                r[e] += Ps[u][s * 9 + e];
        float4* o = (float4*)(out + (s0 + s) * 8);
        o[0] = make_float4(r[0], r[1], r[2], r[3]);
        o[1] = make_float4(r[4], r[5], r[6], r[7]);
    }
}

extern "C" void kernel_launch(void* const* d_in, const int* in_sizes, int n_in,
                              void* d_out, int out_size, void* d_ws, size_t ws_size,
                              hipStream_t stream)
{
    const float* x = (const float*)d_in[0];
    const float* w = (const float*)d_in[1];
    unsigned short* inb = (unsigned short*)d_ws;                                  // 4 MiB
    unsigned short* Ub  = (unsigned short*)((char*)d_ws + (size_t)BATCH * 256 * 2); // 256 KiB
    prep<<<320, 256, 0, stream>>>(x, w, inb, Ub);
    qgemm<<<256, 256, 0, stream>>>(inb, Ub, (float*)d_out);
}